// Round 2
// baseline (692.327 us; speedup 1.0000x reference)
//
#include <hip/hip_runtime.h>
#include <hip/hip_bf16.h>
#include <math.h>

typedef __attribute__((ext_vector_type(8))) short short8;
typedef __attribute__((ext_vector_type(4))) float f32x4;
typedef __attribute__((ext_vector_type(4))) unsigned int uint4v;

#define HIDDEN 1024
#define QOUT 2048
#define KVOUT 1024
#define HD 128
#define NQ 16
#define NKV 8
#define TSEQ 2048
#define BATCH 2
#define NTOK 4096

__device__ __forceinline__ unsigned short f2bf(float f) {
    union { float f; unsigned int u; } x; x.f = f;
    unsigned int r = (x.u + 0x7fffu + ((x.u >> 16) & 1u)) >> 16;
    return (unsigned short)r;
}

// ---------------- cast x (fp32) -> bf16 ----------------
__global__ __launch_bounds__(256) void cast_f32_bf16(const float* __restrict__ in,
                                                     unsigned short* __restrict__ out, int n4) {
    int i = blockIdx.x * 256 + threadIdx.x;
    if (i >= n4) return;
    float4 v = *(const float4*)(in + (size_t)i * 4);
    unsigned short o[4] = {f2bf(v.x), f2bf(v.y), f2bf(v.z), f2bf(v.w)};
    *(unsigned long long*)(out + (size_t)i * 4) = *(unsigned long long*)o;
}

// ---------------- weight transpose: W (K x N) fp32 row-major -> Wt (N x K) bf16 ----------------
__global__ __launch_bounds__(256) void transpose_f32_bf16(const float* __restrict__ W,
                                                          unsigned short* __restrict__ Wt,
                                                          int K, int N) {
    __shared__ __attribute__((aligned(16))) unsigned short Ls[64 * 72];
    int ntiles = N >> 6;
    int kt = blockIdx.x / ntiles, nt = blockIdx.x - kt * ntiles;
    int k0 = kt * 64, n0 = nt * 64;
    int tid = threadIdx.x;
    for (int t = 0; t < 4; t++) {
        int idx = tid + t * 256;       // 1024 slots: 64 rows x 16 col-segs (float4)
        int r = idx >> 4, seg = idx & 15;
        float4 v = *(const float4*)(W + (size_t)(k0 + r) * N + n0 + seg * 4);
        int c = seg * 4;
        Ls[(c + 0) * 72 + r] = f2bf(v.x);
        Ls[(c + 1) * 72 + r] = f2bf(v.y);
        Ls[(c + 2) * 72 + r] = f2bf(v.z);
        Ls[(c + 3) * 72 + r] = f2bf(v.w);
    }
    __syncthreads();
    for (int t = 0; t < 2; t++) {
        int idx = tid + t * 256;       // 512 slots: 64 rows x 8 segs of 8 shorts
        int rr = idx >> 3, seg = idx & 7;
        uint4v v = *(const uint4v*)(Ls + rr * 72 + seg * 8);
        *(uint4v*)(Wt + (size_t)(n0 + rr) * K + k0 + seg * 8) = v;
    }
}

// ---------------- GEMM: C[M,N] = A[M,K](bf16) @ Bt[N,K]^T(bf16) ----------------
// 128x128 block tile, 4 waves (2x2), each wave 64x64 via 4x4 of 16x16x32 MFMA.
template <int OUT_BF16>
__global__ __launch_bounds__(256) void gemm_bt(const unsigned short* __restrict__ A,
                                               const unsigned short* __restrict__ Bt,
                                               void* __restrict__ Cout,
                                               int M, int N, int K) {
    __shared__ __attribute__((aligned(16))) unsigned short As[128 * 40];
    __shared__ __attribute__((aligned(16))) unsigned short Bs[128 * 40];
    const int tid = threadIdx.x;
    const int lane = tid & 63;
    const int warp = tid >> 6;
    const int ln = lane & 15;
    const int quad = lane >> 4;
    const int wm = warp >> 1, wn = warp & 1;
    const int m0 = blockIdx.y * 128;
    const int n0 = blockIdx.x * 128;

    f32x4 acc[4][4];
    for (int i = 0; i < 4; i++)
        for (int j = 0; j < 4; j++) acc[i][j] = (f32x4){0.f, 0.f, 0.f, 0.f};

    for (int k0 = 0; k0 < K; k0 += 32) {
        __syncthreads();
        for (int t = 0; t < 2; t++) {
            int idx = tid + t * 256;
            int row = idx >> 2, seg = idx & 3;
            uint4v av = *(const uint4v*)(A + (size_t)(m0 + row) * K + k0 + seg * 8);
            *(uint4v*)(As + row * 40 + seg * 8) = av;
            uint4v bv = *(const uint4v*)(Bt + (size_t)(n0 + row) * K + k0 + seg * 8);
            *(uint4v*)(Bs + row * 40 + seg * 8) = bv;
        }
        __syncthreads();
        short8 af[4], bf[4];
        for (int mt = 0; mt < 4; mt++)
            af[mt] = *(const short8*)(As + (wm * 64 + mt * 16 + ln) * 40 + quad * 8);
        for (int nt = 0; nt < 4; nt++)
            bf[nt] = *(const short8*)(Bs + (wn * 64 + nt * 16 + ln) * 40 + quad * 8);
        for (int mt = 0; mt < 4; mt++)
            for (int nt = 0; nt < 4; nt++)
                acc[mt][nt] = __builtin_amdgcn_mfma_f32_16x16x32_bf16(af[mt], bf[nt], acc[mt][nt], 0, 0, 0);
    }
    for (int mt = 0; mt < 4; mt++)
        for (int nt = 0; nt < 4; nt++) {
            int col = n0 + wn * 64 + nt * 16 + ln;
            for (int r = 0; r < 4; r++) {
                int row = m0 + wm * 64 + mt * 16 + quad * 4 + r;
                float v = acc[mt][nt][r];
                if (OUT_BF16)
                    ((unsigned short*)Cout)[(size_t)row * N + col] = f2bf(v);
                else
                    ((float*)Cout)[(size_t)row * N + col] = v;
            }
        }
}

// ---------------- fused per-head RMSNorm + RoPE for Q and K ----------------
// one wave per (token, head-slot); slots 0..15 = q heads, 16..23 = k heads
__global__ __launch_bounds__(256) void norm_rope(const float* __restrict__ QKV,
                                                 const float* __restrict__ qw,
                                                 const float* __restrict__ kw,
                                                 unsigned short* __restrict__ Q,
                                                 unsigned short* __restrict__ Kb) {
    int warp = threadIdx.x >> 6;
    int lane = threadIdx.x & 63;
    int gid = blockIdx.x * 4 + warp;
    int tok = gid / 24;
    int slot = gid - tok * 24;
    int b = tok >> 11, t = tok & 2047;
    const float* w;
    unsigned short* dst;
    int col0;
    if (slot < 16) {
        col0 = slot * HD;
        dst = Q + ((size_t)(b * 16 + slot) * TSEQ + t) * HD;
        w = qw;
    } else {
        int hk = slot - 16;
        col0 = QOUT + hk * HD;
        dst = Kb + ((size_t)(b * 8 + hk) * TSEQ + t) * HD;
        w = kw;
    }
    const float* row = QKV + (size_t)tok * 4096 + col0;
    float e0 = row[lane], e1 = row[lane + 64];
    float ss = e0 * e0 + e1 * e1;
    for (int off = 1; off < 64; off <<= 1) ss += __shfl_xor(ss, off);
    float rr = rsqrtf(ss * (1.0f / 128.0f) + 1e-6f);
    float n0 = e0 * rr * w[lane];
    float n1 = e1 * rr * w[lane + 64];
    // RoPE: pair (lane, lane+64), inv_freq = 10000^(-lane/64)
    double invf = pow(10000.0, -(double)lane / 64.0);
    double ang = fmod((double)t * invf, 6.283185307179586476925286766559);
    float cf = cosf((float)ang), sf = sinf((float)ang);
    float o0 = n0 * cf - n1 * sf;
    float o1 = n1 * cf + n0 * sf;
    dst[lane] = f2bf(o0);
    dst[lane + 64] = f2bf(o1);
}

// ---------------- V transpose: QKV v-cols (fp32) -> Vt (b,hk,d,t) bf16 ----------------
__global__ __launch_bounds__(256) void v_transpose(const float* __restrict__ QKV,
                                                   unsigned short* __restrict__ Vt) {
    __shared__ __attribute__((aligned(16))) unsigned short Ls[128 * 72];
    int bid = blockIdx.x;
    int tt = bid & 31, hk = (bid >> 5) & 7, b = bid >> 8;
    int t0 = tt * 64;
    int tid = threadIdx.x;
    const float* base = QKV + (size_t)(b * 2048 + t0) * 4096 + 3072 + hk * 128;
    for (int i = 0; i < 8; i++) {
        int idx = tid + i * 256;
        int r = idx >> 5, c4 = idx & 31;
        float4 v = *(const float4*)(base + (size_t)r * 4096 + c4 * 4);
        int d = c4 * 4;
        Ls[(d + 0) * 72 + r] = f2bf(v.x);
        Ls[(d + 1) * 72 + r] = f2bf(v.y);
        Ls[(d + 2) * 72 + r] = f2bf(v.z);
        Ls[(d + 3) * 72 + r] = f2bf(v.w);
    }
    __syncthreads();
    unsigned short* out = Vt + (size_t)(b * 8 + hk) * 128 * 2048;
    for (int i = 0; i < 4; i++) {
        int idx = tid + i * 256;
        int d = idx >> 3, seg = idx & 7;
        uint4v v = *(const uint4v*)(Ls + d * 72 + seg * 8);
        *(uint4v*)(out + (size_t)d * 2048 + t0 + seg * 8) = v;
    }
}

// ---------------- flash attention: causal, GQA (2 q-heads per kv-head) ----------------
// grid (16 qtiles, 32 b*h); 256 threads = 4 waves, each wave owns 32 q rows.
__global__ __launch_bounds__(256) void attn(const unsigned short* __restrict__ Q,
                                            const unsigned short* __restrict__ Kg,
                                            const unsigned short* __restrict__ Vt,
                                            unsigned short* __restrict__ Og) {
    __shared__ __attribute__((aligned(16))) unsigned short Ks[64 * 136];   // K tile (kv, d)
    __shared__ __attribute__((aligned(16))) unsigned short Vs[128 * 72];   // V^T tile (d, kv)
    __shared__ __attribute__((aligned(16))) unsigned short Ps[4][32 * 72]; // per-wave P (q, kv)
    int qt = 15 - (int)blockIdx.x;  // launch big tiles first
    int bh = blockIdx.y;
    int b = bh >> 4, h = bh & 15;
    int hk = h >> 1;
    int tid = threadIdx.x;
    int warp = tid >> 6, lane = tid & 63, ln = lane & 15, quad = lane >> 4;
    int q0 = qt * 128;
    const int qrow_base = q0 + warp * 32;

    const unsigned short* Qbase = Q + ((size_t)(b * 16 + h) * TSEQ + qrow_base) * HD;
    const unsigned short* Kbase = Kg + (size_t)(b * 8 + hk) * TSEQ * HD;
    const unsigned short* Vbase = Vt + (size_t)(b * 8 + hk) * HD * TSEQ;

    short8 qf[2][4];
    for (int mt = 0; mt < 2; mt++)
        for (int kt = 0; kt < 4; kt++)
            qf[mt][kt] = *(const short8*)(Qbase + (size_t)(mt * 16 + ln) * HD + kt * 32 + quad * 8);

    f32x4 o[2][8];
    for (int mt = 0; mt < 2; mt++)
        for (int ot = 0; ot < 8; ot++) o[mt][ot] = (f32x4){0.f, 0.f, 0.f, 0.f};
    float m_st[2][4], l_st[2][4];
    for (int mt = 0; mt < 2; mt++)
        for (int r = 0; r < 4; r++) { m_st[mt][r] = -1e9f; l_st[mt][r] = 0.f; }

    const float scale = 0.08838834764831845f;  // 1/sqrt(128)
    const float LOG2E = 1.4426950408889634f;
    int nTiles = 2 * qt + 2;
    for (int jt = 0; jt < nTiles; jt++) {
        int j0 = jt * 64;
        for (int i = 0; i < 4; i++) {  // K tile: 64 rows x 128 d
            int idx = tid + i * 256;
            int r = idx >> 4, seg = idx & 15;
            uint4v v = *(const uint4v*)(Kbase + (size_t)(j0 + r) * HD + seg * 8);
            *(uint4v*)(Ks + r * 136 + seg * 8) = v;
        }
        for (int i = 0; i < 4; i++) {  // V^T tile: 128 d x 64 kv
            int idx = tid + i * 256;
            int d = idx >> 3, seg = idx & 7;
            uint4v v = *(const uint4v*)(Vbase + (size_t)d * TSEQ + j0 + seg * 8);
            *(uint4v*)(Vs + d * 72 + seg * 8) = v;
        }
        __syncthreads();
        bool active = (j0 <= qrow_base + 31);
        if (active) {
            for (int mt = 0; mt < 2; mt++) {
                f32x4 s[4];
                for (int nt = 0; nt < 4; nt++) s[nt] = (f32x4){0.f, 0.f, 0.f, 0.f};
                for (int kt = 0; kt < 4; kt++)
                    for (int nt = 0; nt < 4; nt++) {
                        short8 bfr = *(const short8*)(Ks + (nt * 16 + ln) * 136 + kt * 32 + quad * 8);
                        s[nt] = __builtin_amdgcn_mfma_f32_16x16x32_bf16(qf[mt][kt], bfr, s[nt], 0, 0, 0);
                    }
                int qrow0 = qrow_base + mt * 16 + quad * 4;
                for (int nt = 0; nt < 4; nt++) {
                    int kvi = j0 + nt * 16 + ln;
                    for (int r = 0; r < 4; r++) {
                        float v = s[nt][r] * scale;
                        s[nt][r] = (kvi > qrow0 + r) ? -1e9f : v;
                    }
                }
                float alpha[4];
                for (int r = 0; r < 4; r++) {
                    float mx = fmaxf(fmaxf(s[0][r], s[1][r]), fmaxf(s[2][r], s[3][r]));
                    for (int off = 1; off < 16; off <<= 1) mx = fmaxf(mx, __shfl_xor(mx, off));
                    float mo = m_st[mt][r];
                    float mn = fmaxf(mo, mx);
                    float al = exp2f((mo - mn) * LOG2E);
                    float sum = 0.f;
                    for (int nt = 0; nt < 4; nt++) {
                        float p = exp2f((s[nt][r] - mn) * LOG2E);
                        s[nt][r] = p;
                        sum += p;
                    }
                    for (int off = 1; off < 16; off <<= 1) sum += __shfl_xor(sum, off);
                    m_st[mt][r] = mn;
                    l_st[mt][r] = l_st[mt][r] * al + sum;
                    alpha[r] = al;
                }
                for (int ot = 0; ot < 8; ot++)
                    for (int r = 0; r < 4; r++) o[mt][ot][r] *= alpha[r];
                for (int nt = 0; nt < 4; nt++)
                    for (int r = 0; r < 4; r++)
                        Ps[warp][(mt * 16 + quad * 4 + r) * 72 + nt * 16 + ln] = f2bf(s[nt][r]);
            }
            // P @ V^T
            short8 pf[2][2];
            for (int mt = 0; mt < 2; mt++)
                for (int k2 = 0; k2 < 2; k2++)
                    pf[mt][k2] = *(const short8*)(&Ps[warp][(mt * 16 + ln) * 72 + k2 * 32 + quad * 8]);
            for (int ot = 0; ot < 8; ot++) {
                short8 vf0 = *(const short8*)(Vs + (ot * 16 + ln) * 72 + quad * 8);
                short8 vf1 = *(const short8*)(Vs + (ot * 16 + ln) * 72 + 32 + quad * 8);
                for (int mt = 0; mt < 2; mt++) {
                    o[mt][ot] = __builtin_amdgcn_mfma_f32_16x16x32_bf16(pf[mt][0], vf0, o[mt][ot], 0, 0, 0);
                    o[mt][ot] = __builtin_amdgcn_mfma_f32_16x16x32_bf16(pf[mt][1], vf1, o[mt][ot], 0, 0, 0);
                }
            }
        }
        __syncthreads();
    }
    for (int mt = 0; mt < 2; mt++) {
        float inv[4];
        for (int r = 0; r < 4; r++) inv[r] = 1.0f / l_st[mt][r];
        for (int ot = 0; ot < 8; ot++) {
            int col = h * 128 + ot * 16 + ln;
            for (int r = 0; r < 4; r++) {
                int row = qrow_base + mt * 16 + quad * 4 + r;
                Og[((size_t)(b * TSEQ + row)) * QOUT + col] = f2bf(o[mt][ot][r] * inv[r]);
            }
        }
    }
}

extern "C" void kernel_launch(void* const* d_in, const int* in_sizes, int n_in,
                              void* d_out, int out_size, void* d_ws, size_t ws_size,
                              hipStream_t stream) {
    (void)in_sizes; (void)n_in; (void)out_size;
    const float* x  = (const float*)d_in[0];
    const float* Wq = (const float*)d_in[1];
    const float* Wk = (const float*)d_in[2];
    const float* Wv = (const float*)d_in[3];
    const float* Wo = (const float*)d_in[4];
    const float* qw = (const float*)d_in[5];
    const float* kw = (const float*)d_in[6];

    char* ws = (char*)d_ws;
    const size_t MB = 1024 * 1024;
    // layout: Wt (0..8MB) | Wot (8..12MB) | QKV fp32 (12..76MB) | xb (76..84MB, dead after QKV gemm)
    //         Qb (76..92MB) | Kb (92..100MB) | Vtb (100..108MB) | Ob (12..28MB, overlaps dead QKV)
    unsigned short* Wt  = (unsigned short*)(ws);
    unsigned short* Wot = (unsigned short*)(ws + 8 * MB);
    float*          QKV = (float*)(ws + 12 * MB);
    unsigned short* xb  = (unsigned short*)(ws + 76 * MB);
    unsigned short* Qb  = (unsigned short*)(ws + 76 * MB);  // reuses xb space (dead by then)
    unsigned short* Kb  = (unsigned short*)(ws + 92 * MB);
    unsigned short* Vtb = (unsigned short*)(ws + 100 * MB);
    unsigned short* Ob  = (unsigned short*)(ws + 12 * MB);  // overlaps QKV (dead by then)
    if (ws_size < 108 * MB) return;  // insufficient workspace -> visible failure

    // 0. x -> bf16
    cast_f32_bf16<<<dim3(4096), 256, 0, stream>>>(x, xb, 1048576);
    // 1. transpose weights to (N, K) bf16: Wt = [Wq^T ; Wk^T ; Wv^T], Wot = Wo^T
    transpose_f32_bf16<<<dim3(512), 256, 0, stream>>>(Wq, Wt, 1024, 2048);
    transpose_f32_bf16<<<dim3(256), 256, 0, stream>>>(Wk, Wt + (size_t)2048 * 1024, 1024, 1024);
    transpose_f32_bf16<<<dim3(256), 256, 0, stream>>>(Wv, Wt + (size_t)3072 * 1024, 1024, 1024);
    transpose_f32_bf16<<<dim3(512), 256, 0, stream>>>(Wo, Wot, 2048, 1024);
    // 2. QKV = x @ [Wq|Wk|Wv]  (fp32 out)
    gemm_bt<0><<<dim3(32, 32), 256, 0, stream>>>(xb, Wt, QKV, 4096, 4096, 1024);
    // 3. RMSNorm + RoPE for q,k -> bf16 (b,h,t,d)
    norm_rope<<<dim3(24576), 256, 0, stream>>>(QKV, qw, kw, Qb, Kb);
    // 4. V -> bf16 (b,hk,d,t)
    v_transpose<<<dim3(512), 256, 0, stream>>>(QKV, Vtb);
    // 5. causal GQA flash attention -> Ob (b,t,2048) bf16
    attn<<<dim3(16, 32), 256, 0, stream>>>(Qb, Kb, Vtb, Ob);
    // 6. out = Ob @ Wo  (fp32 out)
    gemm_bt<0><<<dim3(8, 32), 256, 0, stream>>>(Ob, Wot, (float*)d_out, 4096, 1024, 2048);
}

// Round 3
// 352.624 us; speedup vs baseline: 1.9634x; 1.9634x over previous
//
#include <hip/hip_runtime.h>
#include <math.h>

typedef __attribute__((ext_vector_type(8))) short short8;
typedef __attribute__((ext_vector_type(4))) float f32x4;
typedef __attribute__((ext_vector_type(4))) unsigned int uint4v;

#define HIDDEN 1024
#define QOUT 2048
#define KVOUT 1024
#define HD 128
#define TSEQ 2048

__device__ __forceinline__ unsigned short f2bf(float f) {
    union { float f; unsigned int u; } x; x.f = f;
    unsigned int r = (x.u + 0x7fffu + ((x.u >> 16) & 1u)) >> 16;
    return (unsigned short)r;
}

// async global->LDS, 16B per lane; dest = wave-uniform base + lane*16
__device__ __forceinline__ void glds16(const unsigned short* g, unsigned short* l) {
    __builtin_amdgcn_global_load_lds(
        (const __attribute__((address_space(1))) unsigned int*)g,
        (__attribute__((address_space(3))) unsigned int*)l, 16, 0, 0);
}

// ---------------- cast x (fp32) -> bf16 ----------------
__global__ __launch_bounds__(256) void cast_f32_bf16(const float* __restrict__ in,
                                                     unsigned short* __restrict__ out, int n4) {
    int i = blockIdx.x * 256 + threadIdx.x;
    if (i >= n4) return;
    float4 v = *(const float4*)(in + (size_t)i * 4);
    unsigned short o[4] = {f2bf(v.x), f2bf(v.y), f2bf(v.z), f2bf(v.w)};
    *(unsigned long long*)(out + (size_t)i * 4) = *(unsigned long long*)o;
}

// ---------------- weight transpose: W (K x N) fp32 row-major -> Wt (N x K) bf16 ----------------
__global__ __launch_bounds__(256) void transpose_f32_bf16(const float* __restrict__ W,
                                                          unsigned short* __restrict__ Wt,
                                                          int K, int N) {
    __shared__ __attribute__((aligned(16))) unsigned short Ls[64 * 72];
    int ntiles = N >> 6;
    int kt = blockIdx.x / ntiles, nt = blockIdx.x - kt * ntiles;
    int k0 = kt * 64, n0 = nt * 64;
    int tid = threadIdx.x;
    for (int t = 0; t < 4; t++) {
        int idx = tid + t * 256;
        int r = idx >> 4, seg = idx & 15;
        float4 v = *(const float4*)(W + (size_t)(k0 + r) * N + n0 + seg * 4);
        int c = seg * 4;
        Ls[(c + 0) * 72 + r] = f2bf(v.x);
        Ls[(c + 1) * 72 + r] = f2bf(v.y);
        Ls[(c + 2) * 72 + r] = f2bf(v.z);
        Ls[(c + 3) * 72 + r] = f2bf(v.w);
    }
    __syncthreads();
    for (int t = 0; t < 2; t++) {
        int idx = tid + t * 256;
        int rr = idx >> 3, seg = idx & 7;
        uint4v v = *(const uint4v*)(Ls + rr * 72 + seg * 8);
        *(uint4v*)(Wt + (size_t)(n0 + rr) * K + k0 + seg * 8) = v;
    }
}

// ---------------- GEMM: C[M,N] = A[M,K](bf16) @ Bt[N,K]^T(bf16), global_load_lds staging ------
template <int OUT_BF16>
__global__ __launch_bounds__(256) void gemm_bt(const unsigned short* __restrict__ A,
                                               const unsigned short* __restrict__ Bt,
                                               void* __restrict__ Cout,
                                               int M, int N, int K) {
    __shared__ __attribute__((aligned(16))) unsigned short As[128 * 32];
    __shared__ __attribute__((aligned(16))) unsigned short Bs[128 * 32];
    const int tid = threadIdx.x;
    const int lane = tid & 63;
    const int warp = tid >> 6;
    const int ln = lane & 15;
    const int quad = lane >> 4;
    const int wm = warp >> 1, wn = warp & 1;
    const int m0 = blockIdx.y * 128;
    const int n0 = blockIdx.x * 128;

    // per-lane source; dest = wave base + lane*16B -> row warp*16+lane/4, seg lane&3
    const unsigned short* Ag = A + (size_t)(m0 + warp * 16 + (lane >> 2)) * K + (lane & 3) * 8;
    const unsigned short* Bg = Bt + (size_t)(n0 + warp * 16 + (lane >> 2)) * K + (lane & 3) * 8;
    unsigned short* AsW = As + warp * 16 * 32;
    unsigned short* BsW = Bs + warp * 16 * 32;

    f32x4 acc[4][4];
    for (int i = 0; i < 4; i++)
        for (int j = 0; j < 4; j++) acc[i][j] = (f32x4){0.f, 0.f, 0.f, 0.f};

    for (int k0 = 0; k0 < K; k0 += 32) {
        __syncthreads();
        glds16(Ag + k0, AsW);
        glds16(Ag + (size_t)64 * K + k0, AsW + 64 * 32);
        glds16(Bg + k0, BsW);
        glds16(Bg + (size_t)64 * K + k0, BsW + 64 * 32);
        __syncthreads();
        short8 af[4], bf[4];
        for (int mt = 0; mt < 4; mt++)
            af[mt] = *(const short8*)(As + (wm * 64 + mt * 16 + ln) * 32 + quad * 8);
        for (int nt = 0; nt < 4; nt++)
            bf[nt] = *(const short8*)(Bs + (wn * 64 + nt * 16 + ln) * 32 + quad * 8);
        for (int mt = 0; mt < 4; mt++)
            for (int nt = 0; nt < 4; nt++)
                acc[mt][nt] = __builtin_amdgcn_mfma_f32_16x16x32_bf16(af[mt], bf[nt], acc[mt][nt], 0, 0, 0);
    }
    for (int mt = 0; mt < 4; mt++)
        for (int nt = 0; nt < 4; nt++) {
            int col = n0 + wn * 64 + nt * 16 + ln;
            for (int r = 0; r < 4; r++) {
                int row = m0 + wm * 64 + mt * 16 + quad * 4 + r;
                float v = acc[mt][nt][r];
                if (OUT_BF16)
                    ((unsigned short*)Cout)[(size_t)row * N + col] = f2bf(v);
                else
                    ((float*)Cout)[(size_t)row * N + col] = v;
            }
        }
}

// ---------------- fused per-head RMSNorm + RoPE for Q and K (fp32 math) ----------------
__global__ __launch_bounds__(256) void norm_rope(const float* __restrict__ QKV,
                                                 const float* __restrict__ qw,
                                                 const float* __restrict__ kw,
                                                 unsigned short* __restrict__ Q,
                                                 unsigned short* __restrict__ Kb) {
    int warp = threadIdx.x >> 6;
    int lane = threadIdx.x & 63;
    int gid = blockIdx.x * 4 + warp;
    int tok = gid / 24;
    int slot = gid - tok * 24;
    int b = tok >> 11, t = tok & 2047;
    const float* w;
    unsigned short* dst;
    int col0;
    if (slot < 16) {
        col0 = slot * HD;
        dst = Q + ((size_t)(b * 16 + slot) * TSEQ + t) * HD;
        w = qw;
    } else {
        int hk = slot - 16;
        col0 = QOUT + hk * HD;
        dst = Kb + ((size_t)(b * 8 + hk) * TSEQ + t) * HD;
        w = kw;
    }
    const float* row = QKV + (size_t)tok * 4096 + col0;
    float e0 = row[lane], e1 = row[lane + 64];
    float ss = e0 * e0 + e1 * e1;
    for (int off = 1; off < 64; off <<= 1) ss += __shfl_xor(ss, off);
    float rr = rsqrtf(ss * (1.0f / 128.0f) + 1e-6f);
    float n0 = e0 * rr * w[lane];
    float n1 = e1 * rr * w[lane + 64];
    // inv_freq = 10000^(-lane/64) = exp2(-lane * log2(10000)/64)
    float invf = __builtin_exp2f(-(float)lane * 0.20762050593045951f);
    float ang = (float)t * invf;
    float sf, cf;
    __sincosf(ang, &sf, &cf);  // fast path; arg <= 2047, reduction error ~1e-4 rad << bf16 ulp
    float o0 = n0 * cf - n1 * sf;
    float o1 = n1 * cf + n0 * sf;
    dst[lane] = f2bf(o0);
    dst[lane + 64] = f2bf(o1);
}

// ---------------- V transpose: QKV v-cols (fp32) -> Vt (b,hk,d,t) bf16 ----------------
__global__ __launch_bounds__(256) void v_transpose(const float* __restrict__ QKV,
                                                   unsigned short* __restrict__ Vt) {
    __shared__ __attribute__((aligned(16))) unsigned short Ls[128 * 72];
    int bid = blockIdx.x;
    int tt = bid & 31, hk = (bid >> 5) & 7, b = bid >> 8;
    int t0 = tt * 64;
    int tid = threadIdx.x;
    const float* base = QKV + (size_t)(b * 2048 + t0) * 4096 + 3072 + hk * 128;
    for (int i = 0; i < 8; i++) {
        int idx = tid + i * 256;
        int r = idx >> 5, c4 = idx & 31;
        float4 v = *(const float4*)(base + (size_t)r * 4096 + c4 * 4);
        int d = c4 * 4;
        Ls[(d + 0) * 72 + r] = f2bf(v.x);
        Ls[(d + 1) * 72 + r] = f2bf(v.y);
        Ls[(d + 2) * 72 + r] = f2bf(v.z);
        Ls[(d + 3) * 72 + r] = f2bf(v.w);
    }
    __syncthreads();
    unsigned short* out = Vt + (size_t)(b * 8 + hk) * 128 * 2048;
    for (int i = 0; i < 4; i++) {
        int idx = tid + i * 256;
        int d = idx >> 3, seg = idx & 7;
        uint4v v = *(const uint4v*)(Ls + d * 72 + seg * 8);
        *(uint4v*)(out + (size_t)d * 2048 + t0 + seg * 8) = v;
    }
}

// ---------------- flash attention v2: balanced q-tile pairing, S^T softmax ----------------
// grid (16 pairs, 32 b*h). Block handles q-tiles p and 31-p (64 rows each).
// Each wave owns 16 rows of BOTH tiles (mt=0 -> tile p, mt=1 -> tile 31-p).
__global__ __launch_bounds__(256) void attn(const unsigned short* __restrict__ Q,
                                            const unsigned short* __restrict__ Kg,
                                            const unsigned short* __restrict__ Vt,
                                            unsigned short* __restrict__ Og) {
    __shared__ __attribute__((aligned(16))) unsigned short Ks[64 * 136];   // K tile (kv, d)
    __shared__ __attribute__((aligned(16))) unsigned short Vs[128 * 72];   // V^T tile (d, kv)
    __shared__ __attribute__((aligned(16))) unsigned short Ps[4][32 * 72]; // per-wave P (q, kv)
    const int p = blockIdx.x;          // 0..15
    const int bh = blockIdx.y;
    const int b = bh >> 4, h = bh & 15, hk = h >> 1;
    const int tid = threadIdx.x;
    const int warp = tid >> 6, lane = tid & 63, ln = lane & 15, quad = lane >> 4;
    const int rowbase[2] = { p * 64 + warp * 16, (31 - p) * 64 + warp * 16 };

    const unsigned short* Kbase = Kg + (size_t)(b * 8 + hk) * TSEQ * HD;
    const unsigned short* Vbase = Vt + (size_t)(b * 8 + hk) * HD * TSEQ;
    const unsigned short* Qh = Q + (size_t)(b * 16 + h) * TSEQ * HD;

    short8 qf[2][4];
    for (int mt = 0; mt < 2; mt++)
        for (int kt = 0; kt < 4; kt++)
            qf[mt][kt] = *(const short8*)(Qh + (size_t)(rowbase[mt] + ln) * HD + kt * 32 + quad * 8);

    f32x4 o[2][8];
    for (int mt = 0; mt < 2; mt++)
        for (int ot = 0; ot < 8; ot++) o[mt][ot] = (f32x4){0.f, 0.f, 0.f, 0.f};
    float m_[2] = {-1e30f, -1e30f}, l_[2] = {0.f, 0.f};

    const float scale = 0.08838834764831845f;  // 1/sqrt(128)
    const float LOG2E = 1.4426950408889634f;
    const int nT = 32 - p;
    for (int j = 0; j < nT; j++) {
        const int j0 = j * 64;
        __syncthreads();
        for (int i = 0; i < 4; i++) {  // K tile: 64 x 128
            int idx = tid + i * 256;
            int r = idx >> 4, seg = idx & 15;
            uint4v v = *(const uint4v*)(Kbase + (size_t)(j0 + r) * HD + seg * 8);
            *(uint4v*)(Ks + r * 136 + seg * 8) = v;
        }
        for (int i = 0; i < 4; i++) {  // V^T tile: 128 x 64
            int idx = tid + i * 256;
            int d = idx >> 3, seg = idx & 7;
            uint4v v = *(const uint4v*)(Vbase + (size_t)d * TSEQ + j0 + seg * 8);
            *(uint4v*)(Vs + d * 72 + seg * 8) = v;
        }
        __syncthreads();
        const bool act[2] = { j0 <= rowbase[0] + 15, j0 <= rowbase[1] + 15 };
        for (int mt = 0; mt < 2; mt++) {
            if (!act[mt]) continue;
            // S^T = K (A-op) x Q (B-op): lane holds 16 kv-scores of q-row (rowbase+ln)
            f32x4 s[4];
            for (int kb = 0; kb < 4; kb++) s[kb] = (f32x4){0.f, 0.f, 0.f, 0.f};
            for (int kt = 0; kt < 4; kt++)
                for (int kb = 0; kb < 4; kb++) {
                    short8 kf = *(const short8*)(Ks + (kb * 16 + ln) * 136 + kt * 32 + quad * 8);
                    s[kb] = __builtin_amdgcn_mfma_f32_16x16x32_bf16(kf, qf[mt][kt], s[kb], 0, 0, 0);
                }
            const int qrow = rowbase[mt] + ln;
            float mx = -1e30f;
            for (int kb = 0; kb < 4; kb++)
                for (int r = 0; r < 4; r++) {
                    int kvi = j0 + kb * 16 + quad * 4 + r;
                    float v = s[kb][r] * scale;
                    v = (kvi > qrow) ? -1e30f : v;
                    s[kb][r] = v;
                    mx = fmaxf(mx, v);
                }
            mx = fmaxf(mx, __shfl_xor(mx, 16));
            mx = fmaxf(mx, __shfl_xor(mx, 32));
            float mn = fmaxf(m_[mt], mx);
            float al = __builtin_exp2f((m_[mt] - mn) * LOG2E);
            float sum = 0.f;
            for (int kb = 0; kb < 4; kb++)
                for (int r = 0; r < 4; r++) {
                    float pv = __builtin_exp2f((s[kb][r] - mn) * LOG2E);
                    s[kb][r] = pv;
                    sum += pv;
                }
            sum += __shfl_xor(sum, 16);
            sum += __shfl_xor(sum, 32);
            m_[mt] = mn;
            l_[mt] = l_[mt] * al + sum;
            // pack P row (q = mt*16+ln), cols kb*16+quad*4 .. +3
            for (int kb = 0; kb < 4; kb++) {
                unsigned long long pk =
                    (unsigned long long)f2bf(s[kb][0]) |
                    ((unsigned long long)f2bf(s[kb][1]) << 16) |
                    ((unsigned long long)f2bf(s[kb][2]) << 32) |
                    ((unsigned long long)f2bf(s[kb][3]) << 48);
                *(unsigned long long*)(&Ps[warp][(mt * 16 + ln) * 72 + kb * 16 + quad * 4]) = pk;
            }
            // rescale o: its rows are quad*4+r -> fetch alpha from lane (quad*4+r)
            float a4[4];
            for (int r = 0; r < 4; r++) a4[r] = __shfl(al, quad * 4 + r);
            for (int ot = 0; ot < 8; ot++)
                for (int r = 0; r < 4; r++) o[mt][ot][r] *= a4[r];
        }
        // P @ V^T (per-wave Ps, no barrier needed; lgkm ordering is per-wave)
        for (int mt = 0; mt < 2; mt++) {
            if (!act[mt]) continue;
            short8 pf0 = *(const short8*)(&Ps[warp][(mt * 16 + ln) * 72 + quad * 8]);
            short8 pf1 = *(const short8*)(&Ps[warp][(mt * 16 + ln) * 72 + 32 + quad * 8]);
            for (int ot = 0; ot < 8; ot++) {
                short8 vf0 = *(const short8*)(Vs + (ot * 16 + ln) * 72 + quad * 8);
                short8 vf1 = *(const short8*)(Vs + (ot * 16 + ln) * 72 + 32 + quad * 8);
                o[mt][ot] = __builtin_amdgcn_mfma_f32_16x16x32_bf16(pf0, vf0, o[mt][ot], 0, 0, 0);
                o[mt][ot] = __builtin_amdgcn_mfma_f32_16x16x32_bf16(pf1, vf1, o[mt][ot], 0, 0, 0);
            }
        }
    }
    for (int mt = 0; mt < 2; mt++) {
        float inv[4];
        for (int r = 0; r < 4; r++) inv[r] = 1.0f / __shfl(l_[mt], quad * 4 + r);
        for (int ot = 0; ot < 8; ot++) {
            int col = h * 128 + ot * 16 + ln;
            for (int r = 0; r < 4; r++) {
                int row = rowbase[mt] + quad * 4 + r;
                Og[((size_t)(b * TSEQ + row)) * QOUT + col] = f2bf(o[mt][ot][r] * inv[r]);
            }
        }
    }
}

extern "C" void kernel_launch(void* const* d_in, const int* in_sizes, int n_in,
                              void* d_out, int out_size, void* d_ws, size_t ws_size,
                              hipStream_t stream) {
    (void)in_sizes; (void)n_in; (void)out_size;
    const float* x  = (const float*)d_in[0];
    const float* Wq = (const float*)d_in[1];
    const float* Wk = (const float*)d_in[2];
    const float* Wv = (const float*)d_in[3];
    const float* Wo = (const float*)d_in[4];
    const float* qw = (const float*)d_in[5];
    const float* kw = (const float*)d_in[6];

    char* ws = (char*)d_ws;
    const size_t MB = 1024 * 1024;
    unsigned short* Wt  = (unsigned short*)(ws);
    unsigned short* Wot = (unsigned short*)(ws + 8 * MB);
    float*          QKV = (float*)(ws + 12 * MB);
    unsigned short* xb  = (unsigned short*)(ws + 76 * MB);
    unsigned short* Qb  = (unsigned short*)(ws + 76 * MB);  // reuses xb (dead by then)
    unsigned short* Kb  = (unsigned short*)(ws + 92 * MB);
    unsigned short* Vtb = (unsigned short*)(ws + 100 * MB);
    unsigned short* Ob  = (unsigned short*)(ws + 12 * MB);  // overlaps QKV (dead by then)
    if (ws_size < 108 * MB) return;

    cast_f32_bf16<<<dim3(4096), 256, 0, stream>>>(x, xb, 1048576);
    transpose_f32_bf16<<<dim3(512), 256, 0, stream>>>(Wq, Wt, 1024, 2048);
    transpose_f32_bf16<<<dim3(256), 256, 0, stream>>>(Wk, Wt + (size_t)2048 * 1024, 1024, 1024);
    transpose_f32_bf16<<<dim3(256), 256, 0, stream>>>(Wv, Wt + (size_t)3072 * 1024, 1024, 1024);
    transpose_f32_bf16<<<dim3(512), 256, 0, stream>>>(Wo, Wot, 2048, 1024);
    gemm_bt<0><<<dim3(32, 32), 256, 0, stream>>>(xb, Wt, QKV, 4096, 4096, 1024);
    norm_rope<<<dim3(24576), 256, 0, stream>>>(QKV, qw, kw, Qb, Kb);
    v_transpose<<<dim3(512), 256, 0, stream>>>(QKV, Vtb);
    attn<<<dim3(16, 32), 256, 0, stream>>>(Qb, Kb, Vtb, Ob);
    gemm_bt<0><<<dim3(8, 32), 256, 0, stream>>>(Ob, Wot, (float*)d_out, 4096, 1024, 2048);
}

// Round 4
// 312.252 us; speedup vs baseline: 2.2172x; 1.1293x over previous
//
#include <hip/hip_runtime.h>
#include <math.h>

typedef __attribute__((ext_vector_type(8))) short short8;
typedef __attribute__((ext_vector_type(4))) float f32x4;
typedef __attribute__((ext_vector_type(4))) unsigned int uint4v;

#define HIDDEN 1024
#define QOUT 2048
#define KVOUT 1024
#define HD 128
#define TSEQ 2048

__device__ __forceinline__ unsigned short f2bf(float f) {
    union { float f; unsigned int u; } x; x.f = f;
    unsigned int r = (x.u + 0x7fffu + ((x.u >> 16) & 1u)) >> 16;
    return (unsigned short)r;
}

// async global->LDS, 16B per lane; dest = wave-uniform base + lane*16
__device__ __forceinline__ void glds16(const unsigned short* g, unsigned short* l) {
    __builtin_amdgcn_global_load_lds(
        (const __attribute__((address_space(1))) unsigned int*)g,
        (__attribute__((address_space(3))) unsigned int*)l, 16, 0, 0);
}

// ---------------- cast x (fp32) -> bf16 ----------------
__global__ __launch_bounds__(256) void cast_f32_bf16(const float* __restrict__ in,
                                                     unsigned short* __restrict__ out, int n4) {
    int i = blockIdx.x * 256 + threadIdx.x;
    if (i >= n4) return;
    float4 v = *(const float4*)(in + (size_t)i * 4);
    unsigned short o[4] = {f2bf(v.x), f2bf(v.y), f2bf(v.z), f2bf(v.w)};
    *(unsigned long long*)(out + (size_t)i * 4) = *(unsigned long long*)o;
}

// ---------------- weight transpose: W (K x N) fp32 row-major -> Wt (N x K) bf16 ----------------
__global__ __launch_bounds__(256) void transpose_f32_bf16(const float* __restrict__ W,
                                                          unsigned short* __restrict__ Wt,
                                                          int K, int N) {
    __shared__ __attribute__((aligned(16))) unsigned short Ls[64 * 72];
    int ntiles = N >> 6;
    int kt = blockIdx.x / ntiles, nt = blockIdx.x - kt * ntiles;
    int k0 = kt * 64, n0 = nt * 64;
    int tid = threadIdx.x;
    for (int t = 0; t < 4; t++) {
        int idx = tid + t * 256;
        int r = idx >> 4, seg = idx & 15;
        float4 v = *(const float4*)(W + (size_t)(k0 + r) * N + n0 + seg * 4);
        int c = seg * 4;
        Ls[(c + 0) * 72 + r] = f2bf(v.x);
        Ls[(c + 1) * 72 + r] = f2bf(v.y);
        Ls[(c + 2) * 72 + r] = f2bf(v.z);
        Ls[(c + 3) * 72 + r] = f2bf(v.w);
    }
    __syncthreads();
    for (int t = 0; t < 2; t++) {
        int idx = tid + t * 256;
        int rr = idx >> 3, seg = idx & 7;
        uint4v v = *(const uint4v*)(Ls + rr * 72 + seg * 8);
        *(uint4v*)(Wt + (size_t)(n0 + rr) * K + k0 + seg * 8) = v;
    }
}

// ---------------- GEMM: C[M,N] = A[M,K](bf16) @ Bt[N,K]^T(bf16), global_load_lds staging ------
// BM=128 fixed; BN = 128 (waves 2x2, 64x64 each) or 64 (waves 4x1, 32x64 each).
template <int OUT_BF16, int BN>
__global__ __launch_bounds__(256) void gemm_bt(const unsigned short* __restrict__ A,
                                               const unsigned short* __restrict__ Bt,
                                               void* __restrict__ Cout,
                                               int M, int N, int K) {
    constexpr int MT = (BN == 128) ? 4 : 2;   // 16-row m-tiles per wave
    __shared__ __attribute__((aligned(16))) unsigned short As[128 * 32];
    __shared__ __attribute__((aligned(16))) unsigned short Bs[BN * 32];
    const int tid = threadIdx.x;
    const int lane = tid & 63;
    const int warp = tid >> 6;
    const int ln = lane & 15;
    const int quad = lane >> 4;
    const int wm = (BN == 128) ? (warp >> 1) : warp;
    const int wn = (BN == 128) ? (warp & 1) : 0;
    const int m0 = blockIdx.y * 128;
    const int n0 = blockIdx.x * BN;

    const unsigned short* Ag = A + (size_t)(m0 + warp * 16 + (lane >> 2)) * K + (lane & 3) * 8;
    const unsigned short* Bg = Bt + (size_t)(n0 + warp * 16 + (lane >> 2)) * K + (lane & 3) * 8;
    unsigned short* AsW = As + warp * 16 * 32;
    unsigned short* BsW = Bs + warp * 16 * 32;

    f32x4 acc[MT][4];
    for (int i = 0; i < MT; i++)
        for (int j = 0; j < 4; j++) acc[i][j] = (f32x4){0.f, 0.f, 0.f, 0.f};

    for (int k0 = 0; k0 < K; k0 += 32) {
        __syncthreads();
        glds16(Ag + k0, AsW);
        glds16(Ag + (size_t)64 * K + k0, AsW + 64 * 32);
        glds16(Bg + k0, BsW);
        if (BN == 128) glds16(Bg + (size_t)64 * K + k0, BsW + 64 * 32);
        __syncthreads();
        short8 af[MT], bf[4];
        for (int mt = 0; mt < MT; mt++)
            af[mt] = *(const short8*)(As + (wm * (MT * 16) + mt * 16 + ln) * 32 + quad * 8);
        for (int nt = 0; nt < 4; nt++)
            bf[nt] = *(const short8*)(Bs + (wn * 64 + nt * 16 + ln) * 32 + quad * 8);
        for (int mt = 0; mt < MT; mt++)
            for (int nt = 0; nt < 4; nt++)
                acc[mt][nt] = __builtin_amdgcn_mfma_f32_16x16x32_bf16(af[mt], bf[nt], acc[mt][nt], 0, 0, 0);
    }
    for (int mt = 0; mt < MT; mt++)
        for (int nt = 0; nt < 4; nt++) {
            int col = n0 + wn * 64 + nt * 16 + ln;
            for (int r = 0; r < 4; r++) {
                int row = m0 + wm * (MT * 16) + mt * 16 + quad * 4 + r;
                float v = acc[mt][nt][r];
                if (OUT_BF16)
                    ((unsigned short*)Cout)[(size_t)row * N + col] = f2bf(v);
                else
                    ((float*)Cout)[(size_t)row * N + col] = v;
            }
        }
}

// ---------------- fused per-head RMSNorm + RoPE for Q and K (fp32 math) ----------------
__global__ __launch_bounds__(256) void norm_rope(const float* __restrict__ QKV,
                                                 const float* __restrict__ qw,
                                                 const float* __restrict__ kw,
                                                 unsigned short* __restrict__ Q,
                                                 unsigned short* __restrict__ Kb) {
    int warp = threadIdx.x >> 6;
    int lane = threadIdx.x & 63;
    int gid = blockIdx.x * 4 + warp;
    int tok = gid / 24;
    int slot = gid - tok * 24;
    int b = tok >> 11, t = tok & 2047;
    const float* w;
    unsigned short* dst;
    int col0;
    if (slot < 16) {
        col0 = slot * HD;
        dst = Q + ((size_t)(b * 16 + slot) * TSEQ + t) * HD;
        w = qw;
    } else {
        int hk = slot - 16;
        col0 = QOUT + hk * HD;
        dst = Kb + ((size_t)(b * 8 + hk) * TSEQ + t) * HD;
        w = kw;
    }
    const float* row = QKV + (size_t)tok * 4096 + col0;
    float e0 = row[lane], e1 = row[lane + 64];
    float ss = e0 * e0 + e1 * e1;
    for (int off = 1; off < 64; off <<= 1) ss += __shfl_xor(ss, off);
    float rr = rsqrtf(ss * (1.0f / 128.0f) + 1e-6f);
    float n0 = e0 * rr * w[lane];
    float n1 = e1 * rr * w[lane + 64];
    float invf = __builtin_exp2f(-(float)lane * 0.20762050593045951f);
    float ang = (float)t * invf;
    float sf, cf;
    __sincosf(ang, &sf, &cf);
    float o0 = n0 * cf - n1 * sf;
    float o1 = n1 * cf + n0 * sf;
    dst[lane] = f2bf(o0);
    dst[lane + 64] = f2bf(o1);
}

// ---------------- V transpose: QKV v-cols (fp32) -> Vt (b,hk,d,t) bf16 ----------------
__global__ __launch_bounds__(256) void v_transpose(const float* __restrict__ QKV,
                                                   unsigned short* __restrict__ Vt) {
    __shared__ __attribute__((aligned(16))) unsigned short Ls[128 * 72];
    int bid = blockIdx.x;
    int tt = bid & 31, hk = (bid >> 5) & 7, b = bid >> 8;
    int t0 = tt * 64;
    int tid = threadIdx.x;
    const float* base = QKV + (size_t)(b * 2048 + t0) * 4096 + 3072 + hk * 128;
    for (int i = 0; i < 8; i++) {
        int idx = tid + i * 256;
        int r = idx >> 5, c4 = idx & 31;
        float4 v = *(const float4*)(base + (size_t)r * 4096 + c4 * 4);
        int d = c4 * 4;
        Ls[(d + 0) * 72 + r] = f2bf(v.x);
        Ls[(d + 1) * 72 + r] = f2bf(v.y);
        Ls[(d + 2) * 72 + r] = f2bf(v.z);
        Ls[(d + 3) * 72 + r] = f2bf(v.w);
    }
    __syncthreads();
    unsigned short* out = Vt + (size_t)(b * 8 + hk) * 128 * 2048;
    for (int i = 0; i < 4; i++) {
        int idx = tid + i * 256;
        int d = idx >> 3, seg = idx & 7;
        uint4v v = *(const uint4v*)(Ls + d * 72 + seg * 8);
        *(uint4v*)(out + (size_t)d * 2048 + t0 + seg * 8) = v;
    }
}

// ---------------- flash attention v3: 8 waves/block, 1 x 16-row strip per wave ----------------
// grid (16 pairs, 32 b*h), 512 threads. Waves 0-3 -> q-tile p, waves 4-7 -> q-tile 31-p.
__global__ __launch_bounds__(512, 4) void attn(const unsigned short* __restrict__ Q,
                                               const unsigned short* __restrict__ Kg,
                                               const unsigned short* __restrict__ Vt,
                                               unsigned short* __restrict__ Og) {
    __shared__ __attribute__((aligned(16))) unsigned short Ks[64 * 136];   // K tile (kv, d)
    __shared__ __attribute__((aligned(16))) unsigned short Vs[128 * 72];   // V^T tile (d, kv)
    __shared__ __attribute__((aligned(16))) unsigned short Ps[8][16 * 72]; // per-wave P (16 q, 64 kv)
    const int p = blockIdx.x;          // 0..15
    const int bh = blockIdx.y;
    const int b = bh >> 4, h = bh & 15, hk = h >> 1;
    const int tid = threadIdx.x;
    const int warp = tid >> 6, lane = tid & 63, ln = lane & 15, quad = lane >> 4;
    const int tile = (warp < 4) ? p : (31 - p);
    const int rowbase = tile * 64 + (warp & 3) * 16;
    const int jdiag = tile;            // kv-tile index containing this wave's diagonal

    const unsigned short* Kbase = Kg + (size_t)(b * 8 + hk) * TSEQ * HD;
    const unsigned short* Vbase = Vt + (size_t)(b * 8 + hk) * HD * TSEQ;
    const unsigned short* Qh = Q + (size_t)(b * 16 + h) * TSEQ * HD;

    short8 qf[4];
    for (int kt = 0; kt < 4; kt++)
        qf[kt] = *(const short8*)(Qh + (size_t)(rowbase + ln) * HD + kt * 32 + quad * 8);

    f32x4 o[8];
    for (int ot = 0; ot < 8; ot++) o[ot] = (f32x4){0.f, 0.f, 0.f, 0.f};
    float m_ = -1e30f, l_ = 0.f;

    // logits pre-scaled into log2 domain: kscale = (1/sqrt(128)) * log2(e)
    const float kscale = 0.12750580997495268f;
    const int nT = 32 - p;
    for (int j = 0; j < nT; j++) {
        const int j0 = j * 64;
        __syncthreads();
        for (int i = 0; i < 2; i++) {  // K tile: 64 rows x 16 segs = 1024 slots
            int idx = tid + i * 512;
            int r = idx >> 4, seg = idx & 15;
            uint4v v = *(const uint4v*)(Kbase + (size_t)(j0 + r) * HD + seg * 8);
            *(uint4v*)(Ks + r * 136 + seg * 8) = v;
        }
        for (int i = 0; i < 2; i++) {  // V^T tile: 128 rows x 8 segs = 1024 slots
            int idx = tid + i * 512;
            int d = idx >> 3, seg = idx & 7;
            uint4v v = *(const uint4v*)(Vbase + (size_t)d * TSEQ + j0 + seg * 8);
            *(uint4v*)(Vs + d * 72 + seg * 8) = v;
        }
        __syncthreads();
        if (j > jdiag) continue;
        // S^T = K (A-op) x Q (B-op): lane holds 16 kv-scores of q-row (rowbase+ln)
        f32x4 s[4];
        for (int kb = 0; kb < 4; kb++) s[kb] = (f32x4){0.f, 0.f, 0.f, 0.f};
        for (int kt = 0; kt < 4; kt++)
            for (int kb = 0; kb < 4; kb++) {
                short8 kf = *(const short8*)(Ks + (kb * 16 + ln) * 136 + kt * 32 + quad * 8);
                s[kb] = __builtin_amdgcn_mfma_f32_16x16x32_bf16(kf, qf[kt], s[kb], 0, 0, 0);
            }
        float mx = -1e30f;
        if (j == jdiag) {  // only the diagonal tile needs masking
            const int qrow = rowbase + ln;
            for (int kb = 0; kb < 4; kb++)
                for (int r = 0; r < 4; r++) {
                    int kvi = j0 + kb * 16 + quad * 4 + r;
                    float v = s[kb][r] * kscale;
                    v = (kvi > qrow) ? -1e30f : v;
                    s[kb][r] = v;
                    mx = fmaxf(mx, v);
                }
        } else {
            for (int kb = 0; kb < 4; kb++)
                for (int r = 0; r < 4; r++) {
                    float v = s[kb][r] * kscale;
                    s[kb][r] = v;
                    mx = fmaxf(mx, v);
                }
        }
        mx = fmaxf(mx, __shfl_xor(mx, 16));
        mx = fmaxf(mx, __shfl_xor(mx, 32));
        float mn = fmaxf(m_, mx);
        float al = __builtin_exp2f(m_ - mn);
        float sum = 0.f;
        for (int kb = 0; kb < 4; kb++)
            for (int r = 0; r < 4; r++) {
                float pv = __builtin_exp2f(s[kb][r] - mn);
                s[kb][r] = pv;
                sum += pv;
            }
        sum += __shfl_xor(sum, 16);
        sum += __shfl_xor(sum, 32);
        m_ = mn;
        l_ = l_ * al + sum;
        for (int kb = 0; kb < 4; kb++) {
            unsigned long long pk =
                (unsigned long long)f2bf(s[kb][0]) |
                ((unsigned long long)f2bf(s[kb][1]) << 16) |
                ((unsigned long long)f2bf(s[kb][2]) << 32) |
                ((unsigned long long)f2bf(s[kb][3]) << 48);
            *(unsigned long long*)(&Ps[warp][ln * 72 + kb * 16 + quad * 4]) = pk;
        }
        if (__any(al != 1.0f)) {  // skip o-rescale on tiles that didn't move the max
            float a4[4];
            for (int r = 0; r < 4; r++) a4[r] = __shfl(al, quad * 4 + r);
            for (int ot = 0; ot < 8; ot++)
                for (int r = 0; r < 4; r++) o[ot][r] *= a4[r];
        }
        short8 pf0 = *(const short8*)(&Ps[warp][ln * 72 + quad * 8]);
        short8 pf1 = *(const short8*)(&Ps[warp][ln * 72 + 32 + quad * 8]);
        for (int ot = 0; ot < 8; ot++) {
            short8 vf0 = *(const short8*)(Vs + (ot * 16 + ln) * 72 + quad * 8);
            short8 vf1 = *(const short8*)(Vs + (ot * 16 + ln) * 72 + 32 + quad * 8);
            o[ot] = __builtin_amdgcn_mfma_f32_16x16x32_bf16(pf0, vf0, o[ot], 0, 0, 0);
            o[ot] = __builtin_amdgcn_mfma_f32_16x16x32_bf16(pf1, vf1, o[ot], 0, 0, 0);
        }
    }
    float inv[4];
    for (int r = 0; r < 4; r++) inv[r] = 1.0f / __shfl(l_, quad * 4 + r);
    for (int ot = 0; ot < 8; ot++) {
        int col = h * 128 + ot * 16 + ln;
        for (int r = 0; r < 4; r++) {
            int row = rowbase + quad * 4 + r;
            Og[((size_t)(b * TSEQ + row)) * QOUT + col] = f2bf(o[ot][r] * inv[r]);
        }
    }
}

extern "C" void kernel_launch(void* const* d_in, const int* in_sizes, int n_in,
                              void* d_out, int out_size, void* d_ws, size_t ws_size,
                              hipStream_t stream) {
    (void)in_sizes; (void)n_in; (void)out_size;
    const float* x  = (const float*)d_in[0];
    const float* Wq = (const float*)d_in[1];
    const float* Wk = (const float*)d_in[2];
    const float* Wv = (const float*)d_in[3];
    const float* Wo = (const float*)d_in[4];
    const float* qw = (const float*)d_in[5];
    const float* kw = (const float*)d_in[6];

    char* ws = (char*)d_ws;
    const size_t MB = 1024 * 1024;
    unsigned short* Wt  = (unsigned short*)(ws);
    unsigned short* Wot = (unsigned short*)(ws + 8 * MB);
    float*          QKV = (float*)(ws + 12 * MB);
    unsigned short* xb  = (unsigned short*)(ws + 76 * MB);
    unsigned short* Qb  = (unsigned short*)(ws + 76 * MB);  // reuses xb (dead by then)
    unsigned short* Kb  = (unsigned short*)(ws + 92 * MB);
    unsigned short* Vtb = (unsigned short*)(ws + 100 * MB);
    unsigned short* Ob  = (unsigned short*)(ws + 12 * MB);  // overlaps QKV (dead by then)
    if (ws_size < 108 * MB) return;

    cast_f32_bf16<<<dim3(4096), 256, 0, stream>>>(x, xb, 1048576);
    transpose_f32_bf16<<<dim3(512), 256, 0, stream>>>(Wq, Wt, 1024, 2048);
    transpose_f32_bf16<<<dim3(256), 256, 0, stream>>>(Wk, Wt + (size_t)2048 * 1024, 1024, 1024);
    transpose_f32_bf16<<<dim3(256), 256, 0, stream>>>(Wv, Wt + (size_t)3072 * 1024, 1024, 1024);
    transpose_f32_bf16<<<dim3(512), 256, 0, stream>>>(Wo, Wot, 2048, 1024);
    gemm_bt<0, 128><<<dim3(32, 32), 256, 0, stream>>>(xb, Wt, QKV, 4096, 4096, 1024);
    norm_rope<<<dim3(24576), 256, 0, stream>>>(QKV, qw, kw, Qb, Kb);
    v_transpose<<<dim3(512), 256, 0, stream>>>(QKV, Vtb);
    attn<<<dim3(16, 32), 512, 0, stream>>>(Qb, Kb, Vtb, Ob);
    gemm_bt<0, 64><<<dim3(16, 32), 256, 0, stream>>>(Ob, Wot, (float*)d_out, 4096, 1024, 2048);
}

// Round 5
// 300.541 us; speedup vs baseline: 2.3036x; 1.0390x over previous
//
#include <hip/hip_runtime.h>
#include <math.h>

typedef __attribute__((ext_vector_type(8))) short short8;
typedef __attribute__((ext_vector_type(4))) float f32x4;
typedef __attribute__((ext_vector_type(4))) unsigned int uint4v;

#define HIDDEN 1024
#define QOUT 2048
#define KVOUT 1024
#define HD 128
#define TSEQ 2048

union U8 { uint4v u; short8 s; };

__device__ __forceinline__ float bf2f(unsigned short h) {
    union { unsigned int u; float f; } x; x.u = ((unsigned int)h) << 16; return x.f;
}
__device__ __forceinline__ unsigned short f2bf(float f) {
    union { float f; unsigned int u; } x; x.f = f;
    unsigned int r = (x.u + 0x7fffu + ((x.u >> 16) & 1u)) >> 16;
    return (unsigned short)r;
}
__device__ __forceinline__ unsigned int pk2bf(float lo, float hi) {
    return (unsigned int)f2bf(lo) | ((unsigned int)f2bf(hi) << 16);
}

// async global->LDS, 16B per lane; dest = wave-uniform base + lane*16
__device__ __forceinline__ void glds16(const unsigned short* g, unsigned short* l) {
    __builtin_amdgcn_global_load_lds(
        (const __attribute__((address_space(1))) unsigned int*)g,
        (__attribute__((address_space(3))) unsigned int*)l, 16, 0, 0);
}

// ---------------- cast x (fp32) -> bf16 ----------------
__global__ __launch_bounds__(256) void cast_f32_bf16(const float* __restrict__ in,
                                                     unsigned short* __restrict__ out, int n4) {
    int i = blockIdx.x * 256 + threadIdx.x;
    if (i >= n4) return;
    float4 v = *(const float4*)(in + (size_t)i * 4);
    unsigned short o[4] = {f2bf(v.x), f2bf(v.y), f2bf(v.z), f2bf(v.w)};
    *(unsigned long long*)(out + (size_t)i * 4) = *(unsigned long long*)o;
}

// ---------------- weight transpose: W (K x N) fp32 row-major -> Wt (N x K) bf16 ----------------
__global__ __launch_bounds__(256) void transpose_f32_bf16(const float* __restrict__ W,
                                                          unsigned short* __restrict__ Wt,
                                                          int K, int N) {
    __shared__ __attribute__((aligned(16))) unsigned short Ls[64 * 72];
    int ntiles = N >> 6;
    int kt = blockIdx.x / ntiles, nt = blockIdx.x - kt * ntiles;
    int k0 = kt * 64, n0 = nt * 64;
    int tid = threadIdx.x;
    for (int t = 0; t < 4; t++) {
        int idx = tid + t * 256;
        int r = idx >> 4, seg = idx & 15;
        float4 v = *(const float4*)(W + (size_t)(k0 + r) * N + n0 + seg * 4);
        int c = seg * 4;
        Ls[(c + 0) * 72 + r] = f2bf(v.x);
        Ls[(c + 1) * 72 + r] = f2bf(v.y);
        Ls[(c + 2) * 72 + r] = f2bf(v.z);
        Ls[(c + 3) * 72 + r] = f2bf(v.w);
    }
    __syncthreads();
    for (int t = 0; t < 2; t++) {
        int idx = tid + t * 256;
        int rr = idx >> 3, seg = idx & 7;
        uint4v v = *(const uint4v*)(Ls + rr * 72 + seg * 8);
        *(uint4v*)(Wt + (size_t)(n0 + rr) * K + k0 + seg * 8) = v;
    }
}

// ---------------- GEMM: C[M,N] = A[M,K](bf16) @ Bt[N,K]^T(bf16) ----------------
// glds16 staging with XOR chunk swizzle (conflict-free ds_read_b128).
template <int OUT_BF16, int BN>
__global__ __launch_bounds__(256) void gemm_bt(const unsigned short* __restrict__ A,
                                               const unsigned short* __restrict__ Bt,
                                               void* __restrict__ Cout,
                                               int M, int N, int K) {
    constexpr int MT = (BN == 128) ? 4 : 2;
    __shared__ __attribute__((aligned(16))) unsigned short As[128 * 32];
    __shared__ __attribute__((aligned(16))) unsigned short Bs[BN * 32];
    const int tid = threadIdx.x;
    const int lane = tid & 63;
    const int warp = tid >> 6;
    const int ln = lane & 15;
    const int quad = lane >> 4;
    const int wm = (BN == 128) ? (warp >> 1) : warp;
    const int wn = (BN == 128) ? (warp & 1) : 0;
    const int m0 = blockIdx.y * 128;
    const int n0 = blockIdx.x * BN;

    // lane -> (row = lane>>2, chunk = lane&3); source chunk XOR-swizzled by row&3
    const int srow = lane >> 2;
    const int schunk = (lane & 3) ^ (srow & 3);
    const unsigned short* Ag = A + (size_t)(m0 + warp * 16 + srow) * K + schunk * 8;
    const unsigned short* Bg = Bt + (size_t)(n0 + warp * 16 + srow) * K + schunk * 8;
    unsigned short* AsW = As + warp * 16 * 32;
    unsigned short* BsW = Bs + warp * 16 * 32;

    f32x4 acc[MT][4];
    for (int i = 0; i < MT; i++)
        for (int j = 0; j < 4; j++) acc[i][j] = (f32x4){0.f, 0.f, 0.f, 0.f};

    const int rq = quad ^ (ln & 3);   // swizzled read chunk
    for (int k0 = 0; k0 < K; k0 += 32) {
        __syncthreads();
        glds16(Ag + k0, AsW);
        glds16(Ag + (size_t)64 * K + k0, AsW + 64 * 32);
        glds16(Bg + k0, BsW);
        if (BN == 128) glds16(Bg + (size_t)64 * K + k0, BsW + 64 * 32);
        __syncthreads();
        short8 af[MT], bf[4];
        for (int mt = 0; mt < MT; mt++)
            af[mt] = *(const short8*)(As + (wm * (MT * 16) + mt * 16 + ln) * 32 + rq * 8);
        for (int nt = 0; nt < 4; nt++)
            bf[nt] = *(const short8*)(Bs + (wn * 64 + nt * 16 + ln) * 32 + rq * 8);
        for (int mt = 0; mt < MT; mt++)
            for (int nt = 0; nt < 4; nt++)
                acc[mt][nt] = __builtin_amdgcn_mfma_f32_16x16x32_bf16(af[mt], bf[nt], acc[mt][nt], 0, 0, 0);
    }
    for (int mt = 0; mt < MT; mt++)
        for (int nt = 0; nt < 4; nt++) {
            int col = n0 + wn * 64 + nt * 16 + ln;
            for (int r = 0; r < 4; r++) {
                int row = m0 + wm * (MT * 16) + mt * 16 + quad * 4 + r;
                float v = acc[mt][nt][r];
                if (OUT_BF16)
                    ((unsigned short*)Cout)[(size_t)row * N + col] = f2bf(v);
                else
                    ((float*)Cout)[(size_t)row * N + col] = v;
            }
        }
}

// ---------------- fused per-head RMSNorm + RoPE for Q and K (bf16 QKV in) ----------------
__global__ __launch_bounds__(256) void norm_rope(const unsigned short* __restrict__ QKV,
                                                 const float* __restrict__ qw,
                                                 const float* __restrict__ kw,
                                                 unsigned short* __restrict__ Q,
                                                 unsigned short* __restrict__ Kb) {
    int warp = threadIdx.x >> 6;
    int lane = threadIdx.x & 63;
    int gid = blockIdx.x * 4 + warp;
    int tok = gid / 24;
    int slot = gid - tok * 24;
    int b = tok >> 11, t = tok & 2047;
    const float* w;
    unsigned short* dst;
    int col0;
    if (slot < 16) {
        col0 = slot * HD;
        dst = Q + ((size_t)(b * 16 + slot) * TSEQ + t) * HD;
        w = qw;
    } else {
        int hk = slot - 16;
        col0 = QOUT + hk * HD;
        dst = Kb + ((size_t)(b * 8 + hk) * TSEQ + t) * HD;
        w = kw;
    }
    const unsigned short* row = QKV + (size_t)tok * 4096 + col0;
    float e0 = bf2f(row[lane]), e1 = bf2f(row[lane + 64]);
    float ss = e0 * e0 + e1 * e1;
    for (int off = 1; off < 64; off <<= 1) ss += __shfl_xor(ss, off);
    float rr = rsqrtf(ss * (1.0f / 128.0f) + 1e-6f);
    float n0 = e0 * rr * w[lane];
    float n1 = e1 * rr * w[lane + 64];
    float invf = __builtin_exp2f(-(float)lane * 0.20762050593045951f);
    float ang = (float)t * invf;
    float sf, cf;
    __sincosf(ang, &sf, &cf);
    float o0 = n0 * cf - n1 * sf;
    float o1 = n1 * cf + n0 * sf;
    dst[lane] = f2bf(o0);
    dst[lane + 64] = f2bf(o1);
}

// ---------------- V transpose: QKV v-cols (bf16) -> Vt (b,hk,d,t) bf16 ----------------
__global__ __launch_bounds__(256) void v_transpose(const unsigned short* __restrict__ QKV,
                                                   unsigned short* __restrict__ Vt) {
    __shared__ __attribute__((aligned(16))) unsigned short Ls[128 * 72];
    int bid = blockIdx.x;
    int tt = bid & 31, hk = (bid >> 5) & 7, b = bid >> 8;
    int t0 = tt * 64;
    int tid = threadIdx.x;
    const unsigned short* base = QKV + (size_t)(b * 2048 + t0) * 4096 + 3072 + hk * 128;
    for (int i = 0; i < 4; i++) {
        int idx = tid + i * 256;          // 1024 slots: 64 rows x 16 chunks(8 shorts)
        int r = idx >> 4, seg = idx & 15;
        uint4v v = *(const uint4v*)(base + (size_t)r * 4096 + seg * 8);
        unsigned short* pv = (unsigned short*)&v;
        int d = seg * 8;
        for (int jj = 0; jj < 8; jj++) Ls[(d + jj) * 72 + r] = pv[jj];
    }
    __syncthreads();
    unsigned short* out = Vt + (size_t)(b * 8 + hk) * 128 * 2048;
    for (int i = 0; i < 4; i++) {
        int idx = tid + i * 256;
        int d = idx >> 3, seg = idx & 7;
        uint4v v = *(const uint4v*)(Ls + d * 72 + seg * 8);
        *(uint4v*)(out + (size_t)d * 2048 + t0 + seg * 8) = v;
    }
}

// ---------------- flash attention v4 ----------------
// grid (16 p, 32 b*h), 256 thr (4 waves). Wave owns 16 rows of tile p (strip 0)
// and 16 rows of tile 31-p (strip 1). Async swizzled K/V staging; P via shuffles.
__global__ __launch_bounds__(256, 2) void attn(const unsigned short* __restrict__ Q,
                                               const unsigned short* __restrict__ Kg,
                                               const unsigned short* __restrict__ Vt,
                                               unsigned short* __restrict__ Og) {
    __shared__ __attribute__((aligned(16))) unsigned short Ks[64 * 128];  // swizzled (kv, d)
    __shared__ __attribute__((aligned(16))) unsigned short Vs[128 * 64];  // swizzled (d, kv)
    const int p = blockIdx.x;          // 0..15
    const int bh = blockIdx.y;
    const int b = bh >> 4, h = bh & 15, hk = h >> 1;
    const int tid = threadIdx.x;
    const int warp = tid >> 6, lane = tid & 63, ln = lane & 15, quad = lane >> 4;
    const int strip[2] = { p * 64 + warp * 16, (31 - p) * 64 + warp * 16 };
    const int jdiag[2] = { p, 31 - p };

    const unsigned short* Kbase = Kg + (size_t)(b * 8 + hk) * TSEQ * HD;
    const unsigned short* Vbase = Vt + (size_t)(b * 8 + hk) * HD * TSEQ;
    const unsigned short* Qh = Q + (size_t)(b * 16 + h) * TSEQ * HD;

    short8 qf[2][4];
    for (int st = 0; st < 2; st++)
        for (int kt = 0; kt < 4; kt++)
            qf[st][kt] = *(const short8*)(Qh + (size_t)(strip[st] + ln) * HD + kt * 32 + quad * 8);

    f32x4 o[2][8];
    for (int st = 0; st < 2; st++)
        for (int ot = 0; ot < 8; ot++) o[st][ot] = (f32x4){0.f, 0.f, 0.f, 0.f};
    float m_[2] = {-1e30f, -1e30f}, l_[2] = {0.f, 0.f};

    // staging lane decomposition
    const int kr = lane >> 4;                 // K: row-in-call (4 rows/call)
    const int kc = lane & 15;                 // K: chunk pos
    const int vr = lane >> 3;                 // V: row-in-call (8 rows/call)
    const int vc = lane & 7;                  // V: chunk pos
    // P-shuffle constants
    const int baseq = (quad & 1) * 2;
    const int i0 = ln + 16 * baseq;
    const int i1 = ln + 16 * (baseq + 1);
    const bool qlow = quad < 2;

    const float kscale = 0.12750580997495268f;  // (1/sqrt(128)) * log2(e)
    const int nT = 32 - p;
    for (int j = 0; j < nT; j++) {
        const int j0 = j * 64;
        __syncthreads();
        // K tile: 64 rows x 128 d, swizzled LDS[r][c] = K[r][c ^ (r&15)]
        for (int c = 0; c < 4; c++) {
            int row = warp * 16 + c * 4 + kr;
            glds16(Kbase + (size_t)(j0 + row) * HD + ((kc ^ (row & 15)) * 8),
                   Ks + (warp * 16 + c * 4) * 128);
        }
        // V^T tile: 128 rows(d) x 64 kv, swizzled LDS[d][c] = V[d][c ^ (d&7)]
        for (int c = 0; c < 4; c++) {
            int d = warp * 32 + c * 8 + vr;
            glds16(Vbase + (size_t)d * TSEQ + j0 + ((vc ^ (d & 7)) * 8),
                   Vs + (warp * 32 + c * 8) * 64);
        }
        __syncthreads();
        for (int st = 0; st < 2; st++) {
            if (j > jdiag[st]) continue;
            // S^T = K x Q: lane(ln,quad) holds kv = j0+kb*16+quad*4+r for q-row strip+ln
            f32x4 s[4];
            for (int kb = 0; kb < 4; kb++) s[kb] = (f32x4){0.f, 0.f, 0.f, 0.f};
            for (int kt = 0; kt < 4; kt++)
                for (int kb = 0; kb < 4; kb++) {
                    short8 kf = *(const short8*)(Ks + (kb * 16 + ln) * 128 + (((kt * 4 + quad) ^ ln) * 8));
                    s[kb] = __builtin_amdgcn_mfma_f32_16x16x32_bf16(kf, qf[st][kt], s[kb], 0, 0, 0);
                }
            float mx = -1e30f;
            if (j == jdiag[st]) {
                const int qloc = warp * 16 + ln;   // q - tile_base (tile == j here)
                for (int kb = 0; kb < 4; kb++)
                    for (int r = 0; r < 4; r++) {
                        int kvloc = kb * 16 + quad * 4 + r;
                        float v = s[kb][r] * kscale;
                        v = (kvloc > qloc) ? -1e30f : v;
                        s[kb][r] = v;
                        mx = fmaxf(mx, v);
                    }
            } else {
                for (int kb = 0; kb < 4; kb++)
                    for (int r = 0; r < 4; r++) {
                        float v = s[kb][r] * kscale;
                        s[kb][r] = v;
                        mx = fmaxf(mx, v);
                    }
            }
            mx = fmaxf(mx, __shfl_xor(mx, 16));
            mx = fmaxf(mx, __shfl_xor(mx, 32));
            float mn = fmaxf(m_[st], mx);
            float al = __builtin_exp2f(m_[st] - mn);
            float sum = 0.f;
            for (int kb = 0; kb < 4; kb++)
                for (int r = 0; r < 4; r++) {
                    float pv = __builtin_exp2f(s[kb][r] - mn);
                    s[kb][r] = pv;
                    sum += pv;
                }
            sum += __shfl_xor(sum, 16);
            sum += __shfl_xor(sum, 32);
            m_[st] = mn;
            l_[st] = l_[st] * al + sum;
            // pack P into bf16 pairs: P2[kb][i] holds kv pair base 16kb+4quad+2i
            unsigned int P2[4][2];
            for (int kb = 0; kb < 4; kb++) {
                P2[kb][0] = pk2bf(s[kb][0], s[kb][1]);
                P2[kb][1] = pk2bf(s[kb][2], s[kb][3]);
            }
            // shuffle into A-operand layout: pf0 kv 0..31, pf1 kv 32..63
            U8 pf0, pf1;
            {
                unsigned a, bb;
                a = __shfl(P2[0][0], i0); bb = __shfl(P2[1][0], i0); pf0.u[0] = qlow ? a : bb;
                a = __shfl(P2[0][1], i0); bb = __shfl(P2[1][1], i0); pf0.u[1] = qlow ? a : bb;
                a = __shfl(P2[0][0], i1); bb = __shfl(P2[1][0], i1); pf0.u[2] = qlow ? a : bb;
                a = __shfl(P2[0][1], i1); bb = __shfl(P2[1][1], i1); pf0.u[3] = qlow ? a : bb;
                a = __shfl(P2[2][0], i0); bb = __shfl(P2[3][0], i0); pf1.u[0] = qlow ? a : bb;
                a = __shfl(P2[2][1], i0); bb = __shfl(P2[3][1], i0); pf1.u[1] = qlow ? a : bb;
                a = __shfl(P2[2][0], i1); bb = __shfl(P2[3][0], i1); pf1.u[2] = qlow ? a : bb;
                a = __shfl(P2[2][1], i1); bb = __shfl(P2[3][1], i1); pf1.u[3] = qlow ? a : bb;
            }
            if (__any(al != 1.0f)) {
                float a4[4];
                for (int r = 0; r < 4; r++) a4[r] = __shfl(al, quad * 4 + r);
                for (int ot = 0; ot < 8; ot++)
                    for (int r = 0; r < 4; r++) o[st][ot][r] *= a4[r];
            }
            for (int ot = 0; ot < 8; ot++) {
                short8 vf0 = *(const short8*)(Vs + (ot * 16 + ln) * 64 + ((quad ^ (ln & 7)) * 8));
                short8 vf1 = *(const short8*)(Vs + (ot * 16 + ln) * 64 + (((4 + quad) ^ (ln & 7)) * 8));
                o[st][ot] = __builtin_amdgcn_mfma_f32_16x16x32_bf16(pf0.s, vf0, o[st][ot], 0, 0, 0);
                o[st][ot] = __builtin_amdgcn_mfma_f32_16x16x32_bf16(pf1.s, vf1, o[st][ot], 0, 0, 0);
            }
        }
    }
    for (int st = 0; st < 2; st++) {
        float inv[4];
        for (int r = 0; r < 4; r++) inv[r] = 1.0f / __shfl(l_[st], quad * 4 + r);
        for (int ot = 0; ot < 8; ot++) {
            int col = h * 128 + ot * 16 + ln;
            for (int r = 0; r < 4; r++) {
                int row = strip[st] + quad * 4 + r;
                Og[((size_t)(b * TSEQ + row)) * QOUT + col] = f2bf(o[st][ot][r] * inv[r]);
            }
        }
    }
}

extern "C" void kernel_launch(void* const* d_in, const int* in_sizes, int n_in,
                              void* d_out, int out_size, void* d_ws, size_t ws_size,
                              hipStream_t stream) {
    (void)in_sizes; (void)n_in; (void)out_size;
    const float* x  = (const float*)d_in[0];
    const float* Wq = (const float*)d_in[1];
    const float* Wk = (const float*)d_in[2];
    const float* Wv = (const float*)d_in[3];
    const float* Wo = (const float*)d_in[4];
    const float* qw = (const float*)d_in[5];
    const float* kw = (const float*)d_in[6];

    char* ws = (char*)d_ws;
    const size_t MB = 1024 * 1024;
    unsigned short* Wt   = (unsigned short*)(ws);            // 8 MB
    unsigned short* Wot  = (unsigned short*)(ws + 8 * MB);   // 4 MB
    unsigned short* QKVb = (unsigned short*)(ws + 12 * MB);  // 32 MB (bf16)
    unsigned short* xb   = (unsigned short*)(ws + 44 * MB);  // 8 MB
    unsigned short* Qb   = (unsigned short*)(ws + 52 * MB);  // 16 MB
    unsigned short* Kb   = (unsigned short*)(ws + 68 * MB);  // 8 MB
    unsigned short* Vtb  = (unsigned short*)(ws + 76 * MB);  // 8 MB
    unsigned short* Ob   = (unsigned short*)(ws + 84 * MB);  // 16 MB
    if (ws_size < 100 * MB) return;

    cast_f32_bf16<<<dim3(4096), 256, 0, stream>>>(x, xb, 1048576);
    transpose_f32_bf16<<<dim3(512), 256, 0, stream>>>(Wq, Wt, 1024, 2048);
    transpose_f32_bf16<<<dim3(256), 256, 0, stream>>>(Wk, Wt + (size_t)2048 * 1024, 1024, 1024);
    transpose_f32_bf16<<<dim3(256), 256, 0, stream>>>(Wv, Wt + (size_t)3072 * 1024, 1024, 1024);
    transpose_f32_bf16<<<dim3(512), 256, 0, stream>>>(Wo, Wot, 2048, 1024);
    gemm_bt<1, 128><<<dim3(32, 32), 256, 0, stream>>>(xb, Wt, QKVb, 4096, 4096, 1024);
    norm_rope<<<dim3(24576), 256, 0, stream>>>(QKVb, qw, kw, Qb, Kb);
    v_transpose<<<dim3(512), 256, 0, stream>>>(QKVb, Vtb);
    attn<<<dim3(16, 32), 256, 0, stream>>>(Qb, Kb, Vtb, Ob);
    gemm_bt<0, 64><<<dim3(16, 32), 256, 0, stream>>>(Ob, Wot, (float*)d_out, 4096, 1024, 2048);
}